// Round 11
// baseline (350.626 us; speedup 1.0000x reference)
//
#include <hip/hip_runtime.h>

#define NDIM 256
#define INNER 512
#define NH 8
#define ND 64
#define NS 32
#define NB 8
#define NP 30208   // padded node count

typedef __attribute__((ext_vector_type(8))) short short8;   // 8 bf16 = 4 VGPR
typedef __attribute__((ext_vector_type(4))) float f32x4;

static __device__ __forceinline__ short f2bf(float f) {
  unsigned u = __float_as_uint(f);
  unsigned r = (u + 0x7fffu + ((u >> 16) & 1u)) >> 16;
  return (short)r;
}
static __device__ __forceinline__ float bf2f(short s) {
  return __uint_as_float(((unsigned)(unsigned short)s) << 16);
}

// async global->LDS, 16 B per lane; dest = uniform lds base + lane*16
static __device__ __forceinline__ void gl_lds16(const void* g, void* l) {
  __builtin_amdgcn_global_load_lds(
      (const __attribute__((address_space(1))) unsigned int*)g,
      (__attribute__((address_space(3))) unsigned int*)l, 16, 0, 0);
}

// ---------------------------------------------------------------------------
// k_xsplit: x fp32 -> Xh/Xl bf16 hi/lo.
// ---------------------------------------------------------------------------
__global__ __launch_bounds__(256) void k_xsplit(
    const float* __restrict__ x, short* __restrict__ Xh, short* __restrict__ Xl,
    int total4)
{
  int id = blockIdx.x * 256 + threadIdx.x;
  if (id >= total4) return;
  float4 v = *(const float4*)&x[(size_t)id * 4];
  short h0 = f2bf(v.x), h1 = f2bf(v.y), h2 = f2bf(v.z), h3 = f2bf(v.w);
  short4 hv = make_short4(h0, h1, h2, h3);
  short4 lv = make_short4(f2bf(v.x - bf2f(h0)), f2bf(v.y - bf2f(h1)),
                          f2bf(v.z - bf2f(h2)), f2bf(v.w - bf2f(h3)));
  *(short4*)&Xh[(size_t)id * 4] = hv;
  *(short4*)&Xl[(size_t)id * 4] = lv;
}

// ---------------------------------------------------------------------------
// k_prep: Bt1 [768][256] bf16 hi/lo, bcomb[256], seg init.
// ---------------------------------------------------------------------------
__global__ __launch_bounds__(256) void k_prep(
    const float* __restrict__ Wfx, const float* __restrict__ Wx,
    const float* __restrict__ bx, const float* __restrict__ Wsl,
    const float* __restrict__ bsl,
    short* __restrict__ Bt1h, short* __restrict__ Bt1l,
    float* __restrict__ bcomb, int* __restrict__ seg)
{
  int id = blockIdx.x * 256 + threadIdx.x;
  if (id < 131072) {
    int k = id >> 9, n = id & 511;
    float v = Wfx[k * 512 + n];
    short hi = f2bf(v); short lo = f2bf(v - bf2f(hi));
    Bt1h[n * 256 + k] = hi; Bt1l[n * 256 + k] = lo;
  } else if (id < 196608) {
    int e = id - 131072;
    int c = e & 255, k = e >> 8;
    int h = c >> 5, s = c & 31;
    float acc = 0.f;
    #pragma unroll 8
    for (int d = 0; d < 64; d++) acc += Wx[k * 512 + h * 64 + d] * Wsl[d * 32 + s];
    short hi = f2bf(acc); short lo = f2bf(acc - bf2f(hi));
    Bt1h[(512 + c) * 256 + k] = hi; Bt1l[(512 + c) * 256 + k] = lo;
  } else if (id < 196864) {
    int c = id - 196608;
    int h = c >> 5, s = c & 31;
    float acc = bsl[s];
    #pragma unroll 8
    for (int d = 0; d < 64; d++) acc += bx[h * 64 + d] * Wsl[d * 32 + s];
    bcomb[c] = acc;
  } else if (id < 196880) {
    int v = id - 196864;
    seg[v] = (v == 0) ? 0 : 0x7fffffff;
  }
}

// ---------------------------------------------------------------------------
// k_segs: multi-block; seg[b] = first index with batch >= b (batch sorted).
// ---------------------------------------------------------------------------
__global__ __launch_bounds__(256) void k_segs(
    const int* __restrict__ batch, int* __restrict__ seg, int N)
{
  int i = blockIdx.x * 256 + threadIdx.x;
  if (i >= N) return;
  int b = batch[i];
  int p = (i == 0) ? -1 : batch[i - 1];
  for (int v = p + 1; v <= b; v++)
    if (v >= 1) atomicMin(&seg[v], i);
  if (i == N - 1)
    for (int v = b + 1; v <= 8; v++) atomicMin(&seg[v], N);
}

// ---------------------------------------------------------------------------
// k_fxw v5.2 (FUSED fxw+scat): per 128-row tile, 6 column-passes of x@Bt1^T
// (round-4 staged K-loop, counted vmcnt(4)) in order {4,0,1,5,2,3}:
// logits passes (4,5) -> softmax w -> global w + wT[2h] LDS stash (+2h saved
// in regs, flushed at ct1/ct3) + snorm atomics.  fx passes (0..3) -> fx
// transposed into fxL LDS per h, then scat MFMAs (stok += wT^T fx) with
// per-segment atomicAdd.  fxT NEVER touches global memory; k_scat deleted.
// v5.1 fix: wT/fxL row stride 136 (17x8, 16B-aligned short8 rows).
// v5.2 fix: non-uniform scat chunk guard was per-lane (quad-dependent) ->
// divergent branch AROUND an MFMA -> skipped lanes left stale A-fragments
// feeding the matrix op -> garbage/NaN on boundary tiles.  Guard is now
// wave-uniform (nc0 = row0+kk*32), fragments always loaded, masking applied
// as per-lane zeroing (VALU cndmask, full-EXEC MFMA) -- the exact discipline
// of the proven k_scat.
// LDS: staging dbuf 64KB [0,32768) + wT 4x4352 [32768,50176) + fxL 2x8704
// [50176,67584) = 135168 B.
// ---------------------------------------------------------------------------
__global__ __launch_bounds__(512) void k_fxw(
    const short* __restrict__ Xh, const short* __restrict__ Xl,
    const short* __restrict__ Bt1h, const short* __restrict__ Bt1l,
    const float* __restrict__ bfx, const float* __restrict__ bcomb,
    const float* __restrict__ gtemp, const int* __restrict__ seg,
    short* __restrict__ wh_out, short* __restrict__ wl_out,
    float* __restrict__ stok, float* __restrict__ snorm,
    int N, int ntiles)
{
  __shared__ __align__(16) short smem[67584];
  const int WT = 32768;    // (plane*2+slot)*4352 ; [32 s][136 n] shorts
  const int FXL = 50176;   // plane*8704 ; [64 d][136 n] shorts

  const int rowt = blockIdx.x;
  if (rowt >= ntiles) return;
  const int row0 = rowt * 128;
  const int tid = threadIdx.x;
  const int lane = tid & 63, l15 = lane & 15, quad = lane >> 4;
  const int wvi = tid >> 6;                  // 0..7
  const int wm = wvi & 1, wn = wvi >> 1;
  const int srow = lane & 15, schunk = lane >> 4;

  // segment info
  int segr[9];
  #pragma unroll
  for (int i = 0; i < 9; i++) segr[i] = seg[i];
  const int tileHi = min(row0 + 128, N);
  int nact = 0, bUni = 0;
  #pragma unroll
  for (int b = 0; b < 8; b++) {
    int lo = max(segr[b], row0), hi = min(segr[b + 1], tileHi);
    if (lo < hi) { nact++; bUni = b; }
  }
  const bool uniform = (nact == 1) && (tileHi - row0 == 128);

  // staging addresses
  int gr = row0 + wvi * 16 + srow;
  if (gr > N - 1) gr = N - 1;                // clamp: finite data, never exec-mask
  const size_t abase = (size_t)gr * 256 + schunk * 8;
  const size_t bthr = (size_t)(wvi * 16 + srow) * 256 + schunk * 8;

#define STAGE(p, ct_, kt_) do {                                                  \
    short* base_ = &smem[(p) * 16384];                                           \
    gl_lds16(Xh + abase + (kt_) * 32, base_ + wvi * 512);                        \
    gl_lds16(Xl + abase + (kt_) * 32, base_ + 4096 + wvi * 512);                 \
    gl_lds16(Bt1h + bthr + (size_t)(ct_) * 32768 + (kt_) * 32, base_ + 8192 + wvi * 512);  \
    gl_lds16(Bt1l + bthr + (size_t)(ct_) * 32768 + (kt_) * 32, base_ + 12288 + wvi * 512); \
  } while (0)

  unsigned wsH[16], wsL[16];   // packed (s0|s1) bf16 w saved by waves wn>=2
  #pragma unroll
  for (int i = 0; i < 16; i++) { wsH[i] = 0; wsL[i] = 0; }

  STAGE(0, 4, 0);   // first pass is ct=4

  for (int pi = 0; pi < 6; pi++) {
    // pass order {4,0,1,5,2,3}
    const int ct = (pi == 0) ? 4 : (pi == 3) ? 5 : (pi < 3 ? pi - 1 : pi - 2);

    f32x4 acc[4][2];
    #pragma unroll
    for (int i = 0; i < 4; i++)
      #pragma unroll
      for (int j = 0; j < 2; j++) acc[i][j] = (f32x4){0.f, 0.f, 0.f, 0.f};

    #pragma unroll
    for (int kt = 0; kt < 8; kt++) {       // K=256, BK=32
      if (kt < 7) {
        STAGE((kt + 1) & 1, ct, kt + 1);
        asm volatile("s_waitcnt vmcnt(4)" ::: "memory");   // current tile landed
      } else {
        asm volatile("s_waitcnt vmcnt(0)" ::: "memory");
      }
      __builtin_amdgcn_s_barrier();
      asm volatile("" ::: "memory");

      const short* AhL = &smem[(kt & 1) * 16384];
      const short* AlL = AhL + 4096;
      const short* BhL = AhL + 8192;
      const short* BlL = AhL + 12288;

      short8 ah[4], al[4];
      #pragma unroll
      for (int mt = 0; mt < 4; mt++) {
        int rg = wm * 4 + mt;
        ah[mt] = *(const short8*)&AhL[rg * 512 + quad * 128 + l15 * 8];
        al[mt] = *(const short8*)&AlL[rg * 512 + quad * 128 + l15 * 8];
      }
      #pragma unroll
      for (int nt = 0; nt < 2; nt++) {
        int rg = wn * 2 + nt;
        short8 bh = *(const short8*)&BhL[rg * 512 + quad * 128 + l15 * 8];
        short8 bl = *(const short8*)&BlL[rg * 512 + quad * 128 + l15 * 8];
        #pragma unroll
        for (int mt = 0; mt < 4; mt++) {
          acc[mt][nt] = __builtin_amdgcn_mfma_f32_16x16x32_bf16(ah[mt], bh, acc[mt][nt], 0, 0, 0);
          acc[mt][nt] = __builtin_amdgcn_mfma_f32_16x16x32_bf16(ah[mt], bl, acc[mt][nt], 0, 0, 0);
          acc[mt][nt] = __builtin_amdgcn_mfma_f32_16x16x32_bf16(al[mt], bh, acc[mt][nt], 0, 0, 0);
        }
      }

      asm volatile("s_waitcnt lgkmcnt(0)" ::: "memory");   // ds_reads drained
      __builtin_amdgcn_s_barrier();                        // buffer-reuse guard
    }

    // prefetch next pass's first tile into buf0 (buf0 fully drained at kt6/7)
    if (pi < 5) {
      const int nct = (pi + 1 == 3) ? 5 : (pi + 1 < 3 ? pi : pi - 1);
      STAGE(0, nct, 0);
    }

    if (ct >= 4) {
      // ---- logits epilogue: softmax -> w global, wT stash / reg save, snorm
      const int h = (ct - 4) * 4 + wn;
      const float inv_t = 1.0f / gtemp[h];
      const int lcb = (ct - 4) * 128 + wn * 32;
      const int lc0 = lcb + l15, lc1 = lcb + 16 + l15;
      const float b0 = bcomb[lc0], b1 = bcomb[lc1];
      float snp0 = 0.f, snp1 = 0.f;
      #pragma unroll
      for (int mt = 0; mt < 4; mt++) {
        #pragma unroll
        for (int r = 0; r < 4; r++) {
          float s0 = (acc[mt][0][r] + b0) * inv_t;
          float s1 = (acc[mt][1][r] + b1) * inv_t;
          float m = fmaxf(s0, s1);
          #pragma unroll
          for (int off = 1; off < 16; off <<= 1) m = fmaxf(m, __shfl_xor(m, off, 16));
          float e0 = __expf(s0 - m), e1 = __expf(s1 - m);
          float sum = e0 + e1;
          #pragma unroll
          for (int off = 1; off < 16; off <<= 1) sum += __shfl_xor(sum, off, 16);
          float inv = 1.0f / sum;
          float w0v = e0 * inv, w1v = e1 * inv;
          int rl = wm * 64 + mt * 16 + quad * 4 + r;   // local row
          int row = row0 + rl;
          short h0 = f2bf(w0v); short l0 = f2bf(w0v - bf2f(h0));
          short h1 = f2bf(w1v); short l1 = f2bf(w1v - bf2f(h1));
          if (row < N) {
            size_t base = (size_t)row * 256;
            wh_out[base + lc0] = h0; wl_out[base + lc0] = l0;
            wh_out[base + lc1] = h1; wl_out[base + lc1] = l1;
          }
          if (wn < 2) {
            // stash into wT slot=wn
            smem[WT + wn * 4352 + l15 * 136 + rl] = h0;
            smem[WT + (2 + wn) * 4352 + l15 * 136 + rl] = l0;
            smem[WT + wn * 4352 + (16 + l15) * 136 + rl] = h1;
            smem[WT + (2 + wn) * 4352 + (16 + l15) * 136 + rl] = l1;
          } else {
            wsH[mt * 4 + r] = (unsigned)(unsigned short)h0 | ((unsigned)(unsigned short)h1 << 16);
            wsL[mt * 4 + r] = (unsigned)(unsigned short)l0 | ((unsigned)(unsigned short)l1 << 16);
          }
          if (uniform) {
            snp0 += w0v; snp1 += w1v;
          } else if (row < tileHi) {
            int be = 0;
            #pragma unroll
            for (int k = 1; k <= 8; k++) be += (segr[k] <= row) ? 1 : 0;
            atomicAdd(&snorm[(be * NH + h) * NS + l15], w0v);
            atomicAdd(&snorm[(be * NH + h) * NS + 16 + l15], w1v);
          }
        }
      }
      if (uniform) {
        atomicAdd(&snorm[(bUni * NH + h) * NS + l15], snp0);
        atomicAdd(&snorm[(bUni * NH + h) * NS + 16 + l15], snp1);
      }
      asm volatile("s_waitcnt lgkmcnt(0)" ::: "memory");
      __builtin_amdgcn_s_barrier();
    } else {
      // ---- fx epilogue: (flush saved wT if ct odd) ; per h: transpose->fxL,
      //      scat MFMAs, atomicAdd stok
      if ((ct & 1) && wvi >= 4) {            // waves wn>=2 flush saved w
        int slot = wn - 2;
        #pragma unroll
        for (int mt = 0; mt < 4; mt++)
          #pragma unroll
          for (int r = 0; r < 4; r++) {
            int rl = wm * 64 + mt * 16 + quad * 4 + r;
            unsigned ph = wsH[mt * 4 + r], pl = wsL[mt * 4 + r];
            smem[WT + slot * 4352 + l15 * 136 + rl] = (short)(ph & 0xffff);
            smem[WT + (2 + slot) * 4352 + l15 * 136 + rl] = (short)(pl & 0xffff);
            smem[WT + slot * 4352 + (16 + l15) * 136 + rl] = (short)(ph >> 16);
            smem[WT + (2 + slot) * 4352 + (16 + l15) * 136 + rl] = (short)(pl >> 16);
          }
      }

      const int sb = wvi & 1, db = wvi >> 1;
      #pragma unroll
      for (int hh = 0; hh < 2; hh++) {
        const int h = ct * 2 + hh;
        // transpose this h's fx cols into fxL (waves owning cols hh*64..+64)
        if ((wn >> 1) == hh) {
          int cw = wn & 1;
          #pragma unroll
          for (int nt = 0; nt < 2; nt++) {
            int d = cw * 32 + nt * 16 + l15;              // 0..63
            float bias = bfx[ct * 128 + hh * 64 + d];
            #pragma unroll
            for (int mt = 0; mt < 4; mt++)
              #pragma unroll
              for (int r = 0; r < 4; r++) {
                int rl = wm * 64 + mt * 16 + quad * 4 + r;
                float v = acc[mt][nt][r] + bias;
                short hi2 = f2bf(v);
                smem[FXL + d * 136 + rl] = hi2;
                smem[FXL + 8704 + d * 136 + rl] = f2bf(v - bf2f(hi2));
              }
          }
        }
        asm volatile("s_waitcnt lgkmcnt(0)" ::: "memory");
        __builtin_amdgcn_s_barrier();

        // scat: stok[b,h, sb*16.., db*16..] += wT^T * fxL
        if (uniform) {
          f32x4 as = (f32x4){0.f, 0.f, 0.f, 0.f};
          #pragma unroll
          for (int kk = 0; kk < 4; kk++) {
            short8 aH = *(const short8*)&smem[WT + hh * 4352 + (sb * 16 + l15) * 136 + kk * 32 + quad * 8];
            short8 aL = *(const short8*)&smem[WT + (2 + hh) * 4352 + (sb * 16 + l15) * 136 + kk * 32 + quad * 8];
            short8 bH = *(const short8*)&smem[FXL + (db * 16 + l15) * 136 + kk * 32 + quad * 8];
            short8 bL = *(const short8*)&smem[FXL + 8704 + (db * 16 + l15) * 136 + kk * 32 + quad * 8];
            as = __builtin_amdgcn_mfma_f32_16x16x32_bf16(aH, bH, as, 0, 0, 0);
            as = __builtin_amdgcn_mfma_f32_16x16x32_bf16(aH, bL, as, 0, 0, 0);
            as = __builtin_amdgcn_mfma_f32_16x16x32_bf16(aL, bH, as, 0, 0, 0);
          }
          size_t base = ((size_t)bUni * NH + h) * NS;
          #pragma unroll
          for (int r = 0; r < 4; r++)
            atomicAdd(&stok[(base + sb * 16 + quad * 4 + r) * ND + db * 16 + l15], as[r]);
        } else {
          #pragma unroll
          for (int b = 0; b < 8; b++) {
            int lo = max(segr[b], row0), hi = min(segr[b + 1], tileHi);
            if (lo >= hi) continue;
            f32x4 as = (f32x4){0.f, 0.f, 0.f, 0.f};
            #pragma unroll
            for (int kk = 0; kk < 4; kk++) {
              int nc0 = row0 + kk * 32;                  // WAVE-UNIFORM chunk base
              if (nc0 + 32 <= lo || nc0 >= hi) continue; // uniform guard: full-EXEC MFMA
              short8 aH = *(const short8*)&smem[WT + hh * 4352 + (sb * 16 + l15) * 136 + kk * 32 + quad * 8];
              short8 aL = *(const short8*)&smem[WT + (2 + hh) * 4352 + (sb * 16 + l15) * 136 + kk * 32 + quad * 8];
              short8 bH = *(const short8*)&smem[FXL + (db * 16 + l15) * 136 + kk * 32 + quad * 8];
              short8 bL = *(const short8*)&smem[FXL + 8704 + (db * 16 + l15) * 136 + kk * 32 + quad * 8];
              int nb = nc0 + quad * 8;                   // per-lane zeroing only
              #pragma unroll
              for (int j = 0; j < 8; j++) {
                int rw = nb + j;
                if (rw < lo || rw >= hi) { aH[j] = 0; aL[j] = 0; }
              }
              as = __builtin_amdgcn_mfma_f32_16x16x32_bf16(aH, bH, as, 0, 0, 0);
              as = __builtin_amdgcn_mfma_f32_16x16x32_bf16(aH, bL, as, 0, 0, 0);
              as = __builtin_amdgcn_mfma_f32_16x16x32_bf16(aL, bH, as, 0, 0, 0);
            }
            size_t base = ((size_t)b * NH + h) * NS;
            #pragma unroll
            for (int r = 0; r < 4; r++)
              atomicAdd(&stok[(base + sb * 16 + quad * 4 + r) * ND + db * 16 + l15], as[r]);
          }
        }
        asm volatile("s_waitcnt lgkmcnt(0)" ::: "memory");
        __builtin_amdgcn_s_barrier();
      }
    }
  }
#undef STAGE
}

// ---------------------------------------------------------------------------
// k_attn: per (b,h): normalize tokens, q/k/v, 32x32 attention, out_tok, then
// P[s][c] = sum_d out_tok[s][d]*Wout[h*64+d][c]; store P^T bf16 hi/lo.
// ---------------------------------------------------------------------------
__global__ __launch_bounds__(256) void k_attn(
    const float* __restrict__ stok, const float* __restrict__ snorm,
    const float* __restrict__ Wq, const float* __restrict__ Wk,
    const float* __restrict__ Wv, const float* __restrict__ Wout,
    short* __restrict__ PTh, short* __restrict__ PTl)
{
  __shared__ __align__(16) float st[32][68];
  __shared__ __align__(16) float qs[32][68];
  __shared__ __align__(16) float ks[32][68];
  __shared__ __align__(16) float vs[32][68];
  __shared__ __align__(16) float at[32][36];
  __shared__ __align__(16) float ot[32][68];
  __shared__ __align__(16) float wo[64][256];   // Wout h-panel, 64 KB

  const int bh = blockIdx.x;
  const int b = bh >> 3, h = bh & 7;
  const int tid = threadIdx.x;
  const int lane = tid & 63;
  const int wv = tid >> 6;

  {
    const float* wsrc = Wout + (size_t)h * 16384;
    float* wdst = &wo[0][0];
    #pragma unroll
    for (int r = 0; r < 16; r++) {
      int off = r * 1024 + wv * 256;            // floats; wave-uniform
      gl_lds16(wsrc + off + lane * 4, wdst + off);
    }
  }

  for (int i = tid; i < 2048; i += 256) {
    int ss = i >> 6, dd = i & 63;
    float nrm = snorm[(size_t)bh * NS + ss] + 1e-5f;
    st[ss][dd] = stok[(size_t)bh * 2048 + i] / nrm;
  }
  __syncthreads();

  {
    float aq[8], ak[8], av[8];
    #pragma unroll
    for (int i = 0; i < 8; i++) { aq[i] = 0.f; ak[i] = 0.f; av[i] = 0.f; }
    for (int ch = 0; ch < 16; ch++) {
      float4 sv[8];
      #pragma unroll
      for (int i = 0; i < 8; i++) sv[i] = *(const float4*)&st[wv * 8 + i][ch * 4];
      #pragma unroll
      for (int d = 0; d < 4; d++) {
        int dd = ch * 4 + d;
        float wq = Wq[dd * 64 + lane];
        float wk = Wk[dd * 64 + lane];
        float wvv = Wv[dd * 64 + lane];
        #pragma unroll
        for (int i = 0; i < 8; i++) {
          float sd = (d == 0) ? sv[i].x : (d == 1) ? sv[i].y : (d == 2) ? sv[i].z : sv[i].w;
          aq[i] = fmaf(sd, wq, aq[i]);
          ak[i] = fmaf(sd, wk, ak[i]);
          av[i] = fmaf(sd, wvv, av[i]);
        }
      }
    }
    #pragma unroll
    for (int i = 0; i < 8; i++) {
      qs[wv * 8 + i][lane] = aq[i];
      ks[wv * 8 + i][lane] = ak[i];
      vs[wv * 8 + i][lane] = av[i];
    }
  }
  __syncthreads();

  {
    const int si = tid >> 3, tj0 = (tid & 7) * 4;
    float a0 = 0.f, a1 = 0.f, a2 = 0.f, a3 = 0.f;
    for (int ch = 0; ch < 16; ch++) {
      float4 q4 = *(const float4*)&qs[si][ch * 4];
      float4 k0 = *(const float4*)&ks[tj0 + 0][ch * 4];
      float4 k1 = *(const float4*)&ks[tj0 + 1][ch * 4];
      float4 k2 = *(const float4*)&ks[tj0 + 2][ch * 4];
      float4 k3 = *(const float4*)&ks[tj0 + 3][ch * 4];
      a0 += q4.x * k0.x + q4.y * k0.y + q4.z * k0.z + q4.w * k0.w;
      a1 += q4.x * k1.x + q4.y * k1.y + q4.z * k1.z + q4.w * k1.w;
      a2 += q4.x * k2.x + q4.y * k2.y + q4.z * k2.z + q4.w * k2.w;
      a3 += q4.x * k3.x + q4.y * k3.y + q4.z * k3.z + q4.w * k3.w;
    }
    const float scale = 0.125f;
    *(float4*)&at[si][tj0] = (float4){a0 * scale, a1 * scale, a2 * scale, a3 * scale};
  }
  __syncthreads();

  {
    const int row = tid >> 3, jb = (tid & 7) * 4;
    float4 v = *(const float4*)&at[row][jb];
    float m = fmaxf(fmaxf(v.x, v.y), fmaxf(v.z, v.w));
    #pragma unroll
    for (int off = 1; off < 8; off <<= 1) m = fmaxf(m, __shfl_xor(m, off, 8));
    float e0 = __expf(v.x - m), e1 = __expf(v.y - m);
    float e2 = __expf(v.z - m), e3 = __expf(v.w - m);
    float s = e0 + e1 + e2 + e3;
    #pragma unroll
    for (int off = 1; off < 8; off <<= 1) s += __shfl_xor(s, off, 8);
    float inv = 1.f / s;
    *(float4*)&at[row][jb] = (float4){e0 * inv, e1 * inv, e2 * inv, e3 * inv};
  }
  __syncthreads();

  {
    float acc[8];
    #pragma unroll
    for (int i = 0; i < 8; i++) acc[i] = 0.f;
    for (int ch = 0; ch < 8; ch++) {
      float v0 = vs[ch * 4 + 0][lane];
      float v1 = vs[ch * 4 + 1][lane];
      float v2 = vs[ch * 4 + 2][lane];
      float v3 = vs[ch * 4 + 3][lane];
      #pragma unroll
      for (int i = 0; i < 8; i++) {
        float4 a4 = *(const float4*)&at[wv * 8 + i][ch * 4];
        acc[i] += a4.x * v0 + a4.y * v1 + a4.z * v2 + a4.w * v3;
      }
    }
    #pragma unroll
    for (int i = 0; i < 8; i++) ot[wv * 8 + i][lane] = acc[i];
  }
  __syncthreads();

  {
    const int c0 = 4 * (lane & 31) + 128 * (lane >> 5);
    float pacc[8][4];
    #pragma unroll
    for (int i = 0; i < 8; i++)
      #pragma unroll
      for (int c = 0; c < 4; c++) pacc[i][c] = 0.f;

    for (int ch = 0; ch < 16; ch++) {
      float4 w0 = *(const float4*)&wo[ch * 4 + 0][c0];
      float4 w1 = *(const float4*)&wo[ch * 4 + 1][c0];
      float4 w2 = *(const float4*)&wo[ch * 4 + 2][c0];
      float4 w3 = *(const float4*)&wo[ch * 4 + 3][c0];
      #pragma unroll
      for (int i = 0; i < 8; i++) {
        float4 o4 = *(const float4*)&ot[wv * 8 + i][ch * 4];
        pacc[i][0] = fmaf(o4.x, w0.x, pacc[i][0]);
        pacc[i][1] = fmaf(o4.x, w0.y, pacc[i][1]);
        pacc[i][2] = fmaf(o4.x, w0.z, pacc[i][2]);
        pacc[i][3] = fmaf(o4.x, w0.w, pacc[i][3]);
        pacc[i][0] = fmaf(o4.y, w1.x, pacc[i][0]);
        pacc[i][1] = fmaf(o4.y, w1.y, pacc[i][1]);
        pacc[i][2] = fmaf(o4.y, w1.z, pacc[i][2]);
        pacc[i][3] = fmaf(o4.y, w1.w, pacc[i][3]);
        pacc[i][0] = fmaf(o4.z, w2.x, pacc[i][0]);
        pacc[i][1] = fmaf(o4.z, w2.y, pacc[i][1]);
        pacc[i][2] = fmaf(o4.z, w2.z, pacc[i][2]);
        pacc[i][3] = fmaf(o4.z, w2.w, pacc[i][3]);
        pacc[i][0] = fmaf(o4.w, w3.x, pacc[i][0]);
        pacc[i][1] = fmaf(o4.w, w3.y, pacc[i][1]);
        pacc[i][2] = fmaf(o4.w, w3.z, pacc[i][2]);
        pacc[i][3] = fmaf(o4.w, w3.w, pacc[i][3]);
      }
    }

    #pragma unroll
    for (int cc = 0; cc < 4; cc++) {
      short8 hv, lv;
      #pragma unroll
      for (int i = 0; i < 8; i++) {
        float val = pacc[i][cc];
        short hi = f2bf(val);
        hv[i] = hi;
        lv[i] = f2bf(val - bf2f(hi));
      }
      size_t dst = ((size_t)b * NDIM + (c0 + cc)) * 256 + h * 32 + wv * 8;
      *(short8*)&PTh[dst] = hv;
      *(short8*)&PTl[dst] = lv;
    }
  }
}

// ---------------------------------------------------------------------------
// k_outw: out[n,c] = sum_{hs} w[n,hs] * PT[batch[n]][c][hs] + bout[c].
// (round-6 verified version)
// ---------------------------------------------------------------------------
__global__ __launch_bounds__(256) void k_outw(
    const short* __restrict__ wh, const short* __restrict__ wl,
    const short* __restrict__ PTh, const short* __restrict__ PTl,
    const int* __restrict__ batch, const float* __restrict__ bout,
    float* __restrict__ out, int N)
{
  __shared__ __align__(16) short smem[32768];
  __shared__ int b_sh[128];

  const int ct = blockIdx.x;
  const int row0 = blockIdx.y * 128;
  const int tid = threadIdx.x;
  const int lane = tid & 63, l15 = lane & 15, quad = lane >> 4;
  const int wv = tid >> 6, wm = wv & 1, wn = wv >> 1;
  const int ctbase = ct * 128;
  const int cnt = min(128, N - row0);

  if (tid < 128) b_sh[tid] = (tid < cnt) ? batch[row0 + tid] : -1;
  __syncthreads();

  f32x4 acc[4][4];
  #pragma unroll
  for (int i = 0; i < 4; i++)
    #pragma unroll
    for (int j = 0; j < 4; j++) acc[i][j] = (f32x4){0.f, 0.f, 0.f, 0.f};

  const bool uniform = (cnt == 128) && (b_sh[0] == b_sh[127]);

  if (uniform) {
    const int b = b_sh[0];
    const int lr = lane >> 2;
    const int csw = (lane & 3) ^ ((lane >> 3) & 3);
    const size_t aoff = (size_t)(row0 + wv * 32 + lr) * 256 + csw * 8;
    const size_t boff = ((size_t)b * 256 + ctbase + wv * 32 + lr) * 256 + csw * 8;

#define OSTAGE(p, kt_) do {                                                    \
    short* base_ = &smem[(p) * 16384];                                         \
    gl_lds16(wh + aoff + (kt_) * 32,        base_ + (wv * 32) * 32);           \
    gl_lds16(wh + aoff + (kt_) * 32 + 4096, base_ + (wv * 32 + 16) * 32);      \
    gl_lds16(wl + aoff + (kt_) * 32,        base_ + 4096 + (wv * 32) * 32);    \
    gl_lds16(wl + aoff + (kt_) * 32 + 4096, base_ + 4096 + (wv * 32 + 16) * 32);\
    gl_lds16(PTh + boff + (kt_) * 32,        base_ + 8192 + (wv * 32) * 32);   \
    gl_lds16(PTh + boff + (kt_) * 32 + 4096, base_ + 8192 + (wv * 32 + 16) * 32);\
    gl_lds16(PTl + boff + (kt_) * 32,        base_ + 12288 + (wv * 32) * 32);  \
    gl_lds16(PTl + boff + (kt_) * 32 + 4096, base_ + 12288 + (wv * 32 + 16) * 32);\
  } while (0)

    OSTAGE(0, 0);

    #pragma unroll
    for (int kt = 0; kt < 8; kt++) {
      if (kt < 7) {
        OSTAGE((kt + 1) & 1, kt + 1);
        asm volatile("s_waitcnt vmcnt(8)" ::: "memory");
      } else {
        asm volatile("s_waitcnt vmcnt(0)" ::: "memory");
      }
      __builtin_amdgcn_s_barrier();
      asm volatile("" ::: "memory");

      const short* AhL = &smem[(kt & 1) * 16384];
      const short* AlL = AhL + 4096;
      const short* BhL = AhL + 8192;
      const short* BlL = AhL + 12288;

      short8 ah[4], al[4];
      #pragma unroll
      for (int mt = 0; mt < 4; mt++) {
        int m = wm * 64 + mt * 16 + l15;
        int q2 = quad ^ ((m >> 1) & 3);
        ah[mt] = *(const short8*)&AhL[m * 32 + q2 * 8];
        al[mt] = *(const short8*)&AlL[m * 32 + q2 * 8];
      }
      #pragma unroll
      for (int nt = 0; nt < 4; nt++) {
        int n = wn * 64 + nt * 16 + l15;
        int q2 = quad ^ ((n >> 1) & 3);
        short8 bh = *(const short8*)&BhL[n * 32 + q2 * 8];
        short8 bl = *(const short8*)&BlL[n * 32 + q2 * 8];
        #pragma unroll
        for (int mt = 0; mt < 4; mt++) {
          acc[mt][nt] = __builtin_amdgcn_mfma_f32_16x16x32_bf16(ah[mt], bh, acc[mt][nt], 0, 0, 0);
          acc[mt][nt] = __builtin_amdgcn_mfma_f32_16x16x32_bf16(ah[mt], bl, acc[mt][nt], 0, 0, 0);
          acc[mt][nt] = __builtin_amdgcn_mfma_f32_16x16x32_bf16(al[mt], bh, acc[mt][nt], 0, 0, 0);
        }
      }

      asm volatile("s_waitcnt lgkmcnt(0)" ::: "memory");
      __builtin_amdgcn_s_barrier();
    }
#undef OSTAGE
  } else {
    short (*Ah)[40] = (short(*)[40])&smem[0];
    short (*Al)[40] = (short(*)[40])&smem[5120];
    short (*Bh)[40] = (short(*)[40])&smem[10240];
    short (*Bl)[40] = (short(*)[40])&smem[15360];

    int i0 = 0;
    while (i0 < cnt) {
      int b = b_sh[i0];
      int j = i0;
      while (j < cnt && b_sh[j] == b) j++;

      for (int kt = 0; kt < 8; kt++) {
        #pragma unroll
        for (int t = 0; t < 2; t++) {
          int i = tid + t * 256;
          int row = i >> 2, kc = (i & 3) * 8;
          int4 vh = make_int4(0, 0, 0, 0), vl = make_int4(0, 0, 0, 0);
          if (row >= i0 && row < j) {
            size_t src = (size_t)(row0 + row) * 256 + kt * 32 + kc;
            vh = *(const int4*)&wh[src];
            vl = *(const int4*)&wl[src];
          }
          *(int4*)&Ah[row][kc] = vh;
          *(int4*)&Al[row][kc] = vl;
        }
        #pragma unroll
        for (int t = 0; t < 2; t++) {
          int i = tid + t * 256;
          int row = i >> 2, kc = (i & 3) * 8;
          size_t src = ((size_t)b * NDIM + ctbase + row) * 256 + kt * 32 + kc;
          *(int4*)&Bh[row][kc] = *(const int4*)&PTh[src];
          *(int4*)&Bl[row][kc] = *(const int4*)&PTl[src];
        }
        __syncthreads();

        short8 ah[4], al[4];
        #pragma unroll
        for (int mt = 0; mt < 4; mt++) {
          int m = wm * 64 + mt * 16 + l15;
          ah[mt] = *(const short8*)&Ah[m][quad * 8];
          al[mt] = *(const short8*)&Al[m][quad * 8];
        }
        #pragma unroll
        for (int nt = 0; nt < 4; nt++) {
          int n = wn * 64 + nt * 16 + l15;
          short8 bh = *(const short8*)&Bh[n][quad * 8];
          short8 bl = *(const short8*)&Bl[n][quad * 8];
          #pragma unroll
          for (int mt = 0; mt < 4; mt++) {
            acc[mt][nt] = __builtin_amdgcn_mfma_f32_16x16x32_bf16(ah[mt], bh, acc[mt][nt], 0, 0, 0);
            acc[mt][nt] = __builtin_amdgcn_mfma_f32_16x16x32_bf16(ah[mt], bl, acc[mt][nt], 0, 0, 0);
            acc[mt][nt] = __builtin_amdgcn_mfma_f32_16x16x32_bf16(al[mt], bh, acc[mt][nt], 0, 0, 0);
          }
        }
        __syncthreads();
      }
      i0 = j;
    }
  }

  #pragma unroll
  for (int nt = 0; nt < 4; nt++) {
    int c = ctbase + wn * 64 + nt * 16 + l15;
    float bias = bout[c];
    #pragma unroll
    for (int mt = 0; mt < 4; mt++)
      #pragma unroll
      for (int r = 0; r < 4; r++) {
        int row = row0 + wm * 64 + mt * 16 + quad * 4 + r;
        if (row < N) out[(size_t)row * NDIM + c] = acc[mt][nt][r] + bias;
      }
  }
}

// ---------------------------------------------------------------------------
extern "C" void kernel_launch(void* const* d_in, const int* in_sizes, int n_in,
                              void* d_out, int out_size, void* d_ws, size_t ws_size,
                              hipStream_t stream) {
  const float* x      = (const float*)d_in[0];
  const int*   batch  = (const int*)d_in[1];
  const float* Wfx    = (const float*)d_in[2];
  const float* bfx    = (const float*)d_in[3];
  const float* Wx     = (const float*)d_in[4];
  const float* bx     = (const float*)d_in[5];
  const float* Wsl    = (const float*)d_in[6];
  const float* bsl    = (const float*)d_in[7];
  const float* gtemp  = (const float*)d_in[8];
  const float* Wq     = (const float*)d_in[9];
  const float* Wk     = (const float*)d_in[10];
  const float* Wv     = (const float*)d_in[11];
  const float* Wout   = (const float*)d_in[12];
  const float* bout   = (const float*)d_in[13];
  float* out = (float*)d_out;

  const int N = in_sizes[0] / NDIM;   // 30000

  float* stok  = (float*)d_ws;                     // 131072
  float* snorm = stok + 131072;                    // 2048
  float* bcomb = snorm + 2048;                     // 256
  int*   seg   = (int*)(bcomb + 256);              // 16
  short* Bt1h  = (short*)(seg + 16);               // 196608
  short* Bt1l  = Bt1h + 196608;
  short* Xh    = Bt1l + 196608;                    // N*256
  short* Xl    = Xh + 7680000;
  short* whb   = Xl + 7680000;                     // NP*256
  short* wlb   = whb + (size_t)NP * 256;
  short* PTh   = wlb + (size_t)NP * 256;           // 524288
  short* PTl   = PTh + 524288;

  hipMemsetAsync(stok, 0, (size_t)(131072 + 2048) * sizeof(float), stream);

  k_xsplit<<<(N * 64 + 255) / 256, 256, 0, stream>>>(x, Xh, Xl, N * 64);

  k_prep<<<770, 256, 0, stream>>>(Wfx, Wx, bx, Wsl, bsl, Bt1h, Bt1l, bcomb, seg);

  k_segs<<<(N + 255) / 256, 256, 0, stream>>>(batch, seg, N);

  const int ntiles = (N + 127) / 128;               // 235
  k_fxw<<<ntiles, 512, 0, stream>>>(Xh, Xl, Bt1h, Bt1l, bfx, bcomb, gtemp, seg,
                                    whb, wlb, stok, snorm, N, ntiles);

  k_attn<<<NB * NH, 256, 0, stream>>>(stok, snorm, Wq, Wk, Wv, Wout, PTh, PTl);

  dim3 g5(2, (N + 127) / 128);
  k_outw<<<g5, 256, 0, stream>>>(whb, wlb, PTh, PTl, batch, bout, out, N);
}

// Round 12
// 265.986 us; speedup vs baseline: 1.3182x; 1.3182x over previous
//
#include <hip/hip_runtime.h>

#define NDIM 256
#define INNER 512
#define NH 8
#define ND 64
#define NS 32
#define NB 8
#define NP 30208   // padded node count

typedef __attribute__((ext_vector_type(8))) short short8;   // 8 bf16 = 4 VGPR
typedef __attribute__((ext_vector_type(4))) float f32x4;

static __device__ __forceinline__ short f2bf(float f) {
  unsigned u = __float_as_uint(f);
  unsigned r = (u + 0x7fffu + ((u >> 16) & 1u)) >> 16;
  return (short)r;
}
static __device__ __forceinline__ float bf2f(short s) {
  return __uint_as_float(((unsigned)(unsigned short)s) << 16);
}

// async global->LDS, 16 B per lane; dest = uniform lds base + lane*16
static __device__ __forceinline__ void gl_lds16(const void* g, void* l) {
  __builtin_amdgcn_global_load_lds(
      (const __attribute__((address_space(1))) unsigned int*)g,
      (__attribute__((address_space(3))) unsigned int*)l, 16, 0, 0);
}

// ---------------------------------------------------------------------------
// k_xsplit: x fp32 -> Xh/Xl bf16 hi/lo.
// ---------------------------------------------------------------------------
__global__ __launch_bounds__(256) void k_xsplit(
    const float* __restrict__ x, short* __restrict__ Xh, short* __restrict__ Xl,
    int total4)
{
  int id = blockIdx.x * 256 + threadIdx.x;
  if (id >= total4) return;
  float4 v = *(const float4*)&x[(size_t)id * 4];
  short h0 = f2bf(v.x), h1 = f2bf(v.y), h2 = f2bf(v.z), h3 = f2bf(v.w);
  short4 hv = make_short4(h0, h1, h2, h3);
  short4 lv = make_short4(f2bf(v.x - bf2f(h0)), f2bf(v.y - bf2f(h1)),
                          f2bf(v.z - bf2f(h2)), f2bf(v.w - bf2f(h3)));
  *(short4*)&Xh[(size_t)id * 4] = hv;
  *(short4*)&Xl[(size_t)id * 4] = lv;
}

// ---------------------------------------------------------------------------
// k_prep: Bt1 [768][256] bf16 hi/lo, bcomb[256], seg init.
// ---------------------------------------------------------------------------
__global__ __launch_bounds__(256) void k_prep(
    const float* __restrict__ Wfx, const float* __restrict__ Wx,
    const float* __restrict__ bx, const float* __restrict__ Wsl,
    const float* __restrict__ bsl,
    short* __restrict__ Bt1h, short* __restrict__ Bt1l,
    float* __restrict__ bcomb, int* __restrict__ seg)
{
  int id = blockIdx.x * 256 + threadIdx.x;
  if (id < 131072) {
    int k = id >> 9, n = id & 511;
    float v = Wfx[k * 512 + n];
    short hi = f2bf(v); short lo = f2bf(v - bf2f(hi));
    Bt1h[n * 256 + k] = hi; Bt1l[n * 256 + k] = lo;
  } else if (id < 196608) {
    int e = id - 131072;
    int c = e & 255, k = e >> 8;
    int h = c >> 5, s = c & 31;
    float acc = 0.f;
    #pragma unroll 8
    for (int d = 0; d < 64; d++) acc += Wx[k * 512 + h * 64 + d] * Wsl[d * 32 + s];
    short hi = f2bf(acc); short lo = f2bf(acc - bf2f(hi));
    Bt1h[(512 + c) * 256 + k] = hi; Bt1l[(512 + c) * 256 + k] = lo;
  } else if (id < 196864) {
    int c = id - 196608;
    int h = c >> 5, s = c & 31;
    float acc = bsl[s];
    #pragma unroll 8
    for (int d = 0; d < 64; d++) acc += bx[h * 64 + d] * Wsl[d * 32 + s];
    bcomb[c] = acc;
  } else if (id < 196880) {
    int v = id - 196864;
    seg[v] = (v == 0) ? 0 : 0x7fffffff;
  }
}

// ---------------------------------------------------------------------------
// k_segs: multi-block; seg[b] = first index with batch >= b (batch sorted).
// Requires seg pre-init (k_prep). seg[8..15] tail = N.
// ---------------------------------------------------------------------------
__global__ __launch_bounds__(256) void k_segs(
    const int* __restrict__ batch, int* __restrict__ seg, int N)
{
  int i = blockIdx.x * 256 + threadIdx.x;
  if (i >= N) return;
  int b = batch[i];
  int p = (i == 0) ? -1 : batch[i - 1];
  for (int v = p + 1; v <= b; v++)
    if (v >= 1) atomicMin(&seg[v], i);
  if (i == N - 1)
    for (int v = b + 1; v <= 8; v++) atomicMin(&seg[v], N);
}

// ---------------------------------------------------------------------------
// k_fxw (round-4 proven version): C[N,768] = x @ Bt1^T, split-3 bf16 MFMA.
// 512 threads / 8 waves; wave (wm,wn) owns a 64x32 output slice (acc[4][2]).
// T3/T4: double-buffered staging (2 x 32KB) with COUNTED vmcnt(4) -- the
// next tile's 4 DMAs/wave stay in flight across the barrier; drain-to-0 only
// on the last tile.  Raw s_barrier (no __syncthreads -> no implicit vmcnt(0)
// drain).  lgkmcnt(0) before the trailing barrier keeps ds_reads from being
// in flight when the buffer is re-staged.
// ---------------------------------------------------------------------------
__global__ __launch_bounds__(512, 4) void k_fxw(
    const short* __restrict__ Xh, const short* __restrict__ Xl,
    const short* __restrict__ Bt1h, const short* __restrict__ Bt1l,
    const float* __restrict__ bfx, const float* __restrict__ bcomb,
    const float* __restrict__ gtemp,
    short* __restrict__ fxTh, short* __restrict__ fxTl,
    short* __restrict__ wh_out, short* __restrict__ wl_out,
    int N, int ntiles)
{
  __shared__ __align__(16) short smem[32768];   // 64 KB: 2 staging buffers

  const int lid = blockIdx.x;
  const int xcd = lid & 7;
  const int idx = lid >> 3;
  const int ct  = idx % 6;
  const int rowt = xcd + 8 * (idx / 6);
  if (rowt >= ntiles) return;
  const int row0 = rowt * 128;
  const int tid = threadIdx.x;
  const int lane = tid & 63, l15 = lane & 15, quad = lane >> 4;
  const int wvi = tid >> 6;                  // 0..7
  const int wm = wvi & 1, wn = wvi >> 1;     // wm row-half, wn col-quarter
  const int ctbase = ct * 128;
  const int srow = lane & 15, schunk = lane >> 4;

  f32x4 acc[4][2];
  #pragma unroll
  for (int i = 0; i < 4; i++)
    #pragma unroll
    for (int j = 0; j < 2; j++) acc[i][j] = (f32x4){0.f, 0.f, 0.f, 0.f};

  // staging addresses (per-thread constants across kt)
  int gr = row0 + wvi * 16 + srow;
  if (gr > N - 1) gr = N - 1;                // clamp: finite data, never exec-mask
  const int br = ctbase + wvi * 16 + srow;
  const size_t abase = (size_t)gr * 256 + schunk * 8;
  const size_t bbase = (size_t)br * 256 + schunk * 8;

#define STAGE(p, kt_) do {                                         \
    short* base_ = &smem[(p) * 16384];                             \
    gl_lds16(Xh + abase + (kt_) * 32, base_ + wvi * 512);          \
    gl_lds16(Xl + abase + (kt_) * 32, base_ + 4096 + wvi * 512);   \
    gl_lds16(Bt1h + bbase + (kt_) * 32, base_ + 8192 + wvi * 512); \
    gl_lds16(Bt1l + bbase + (kt_) * 32, base_ + 12288 + wvi * 512);\
  } while (0)

  STAGE(0, 0);

  #pragma unroll
  for (int kt = 0; kt < 8; kt++) {       // K=256, BK=32
    if (kt < 7) {
      STAGE((kt + 1) & 1, kt + 1);
      asm volatile("s_waitcnt vmcnt(4)" ::: "memory");   // current tile landed
    } else {
      asm volatile("s_waitcnt vmcnt(0)" ::: "memory");
    }
    __builtin_amdgcn_s_barrier();
    asm volatile("" ::: "memory");

    const short* AhL = &smem[(kt & 1) * 16384];
    const short* AlL = AhL + 4096;
    const short* BhL = AhL + 8192;
    const short* BlL = AhL + 12288;

    short8 ah[4], al[4];
    #pragma unroll
    for (int mt = 0; mt < 4; mt++) {
      int rg = wm * 4 + mt;
      ah[mt] = *(const short8*)&AhL[rg * 512 + quad * 128 + l15 * 8];
      al[mt] = *(const short8*)&AlL[rg * 512 + quad * 128 + l15 * 8];
    }
    #pragma unroll
    for (int nt = 0; nt < 2; nt++) {
      int rg = wn * 2 + nt;
      short8 bh = *(const short8*)&BhL[rg * 512 + quad * 128 + l15 * 8];
      short8 bl = *(const short8*)&BlL[rg * 512 + quad * 128 + l15 * 8];
      #pragma unroll
      for (int mt = 0; mt < 4; mt++) {
        acc[mt][nt] = __builtin_amdgcn_mfma_f32_16x16x32_bf16(ah[mt], bh, acc[mt][nt], 0, 0, 0);
        acc[mt][nt] = __builtin_amdgcn_mfma_f32_16x16x32_bf16(ah[mt], bl, acc[mt][nt], 0, 0, 0);
        acc[mt][nt] = __builtin_amdgcn_mfma_f32_16x16x32_bf16(al[mt], bh, acc[mt][nt], 0, 0, 0);
      }
    }

    asm volatile("s_waitcnt lgkmcnt(0)" ::: "memory");   // ds_reads drained
    __builtin_amdgcn_s_barrier();                        // buffer-reuse guard
  }
#undef STAGE

  if (ct < 4) {
    // two-pass LDS transpose -> fxT[c][n] bf16 hi (pass 0) / lo (pass 1)
    short (*T)[136] = (short(*)[136])&smem[0];   // 128 x 136 = 17408 shorts
    #pragma unroll
    for (int pass = 0; pass < 2; pass++) {
      __syncthreads();
      #pragma unroll
      for (int nt = 0; nt < 2; nt++) {
        int cl = wn * 32 + nt * 16 + l15;
        float bias = bfx[ctbase + cl];
        #pragma unroll
        for (int mt = 0; mt < 4; mt++)
          #pragma unroll
          for (int r = 0; r < 4; r++) {
            int rl = wm * 64 + mt * 16 + quad * 4 + r;
            float v = acc[mt][nt][r] + bias;
            short hi2 = f2bf(v);
            T[cl][rl] = pass ? f2bf(v - bf2f(hi2)) : hi2;
          }
      }
      __syncthreads();
      short* dst = pass ? fxTl : fxTh;
      #pragma unroll
      for (int t = 0; t < 4; t++) {
        int idx2 = tid + t * 512;                 // 2048 int4 chunks
        int row = idx2 >> 4, kc = (idx2 & 15) * 8;
        *(int4*)&dst[(size_t)(ctbase + row) * NP + row0 + kc] = *(const int4*)&T[row][kc];
      }
    }
  } else {
    int ct2 = ct - 4;
    int lcbase = ct2 * 128 + wn * 32;            // 32-col (one h) slice per wave
    int h = lcbase >> 5;
    float inv_t = 1.0f / gtemp[h];
    int lc0 = lcbase + l15, lc1 = lcbase + 16 + l15;
    float b0 = bcomb[lc0], b1 = bcomb[lc1];
    #pragma unroll
    for (int mt = 0; mt < 4; mt++) {
      #pragma unroll
      for (int r = 0; r < 4; r++) {
        float s0 = (acc[mt][0][r] + b0) * inv_t;
        float s1 = (acc[mt][1][r] + b1) * inv_t;
        float m = fmaxf(s0, s1);
        #pragma unroll
        for (int off = 1; off < 16; off <<= 1) m = fmaxf(m, __shfl_xor(m, off, 16));
        float e0 = __expf(s0 - m), e1 = __expf(s1 - m);
        float sum = e0 + e1;
        #pragma unroll
        for (int off = 1; off < 16; off <<= 1) sum += __shfl_xor(sum, off, 16);
        float inv = 1.0f / sum;
        int row = row0 + wm * 64 + mt * 16 + quad * 4 + r;
        if (row < N) {
          float w0v = e0 * inv, w1v = e1 * inv;
          size_t base = (size_t)row * (NH * NS);
          short h0 = f2bf(w0v), h1 = f2bf(w1v);
          wh_out[base + lc0] = h0; wl_out[base + lc0] = f2bf(w0v - bf2f(h0));
          wh_out[base + lc1] = h1; wl_out[base + lc1] = f2bf(w1v - bf2f(h1));
        }
      }
    }
  }
}

// ---------------------------------------------------------------------------
// k_scat: slice_token[b,h,s,d] = sum_n w[n,hs]*fx[n,hd], split-3 MFMA over
// K=nodes. w staged via LDS transpose with segment masking folded into the
// store -> A-fragments are ds_read_b128. Per-segment atomic flush.
// ---------------------------------------------------------------------------
__global__ __launch_bounds__(256) void k_scat(
    const short* __restrict__ wh, const short* __restrict__ wl,
    const short* __restrict__ fxTh, const short* __restrict__ fxTl,
    const int* __restrict__ seg,
    float* __restrict__ stok, float* __restrict__ snorm, int N)
{
  __shared__ short wth[32][136];     // [s][n], masked
  __shared__ short wtl[32][136];
  __shared__ short fh[64][136];      // [d][n]
  __shared__ short fl[64][136];
  __shared__ float ln[32];

  const int h = blockIdx.y;
  const int n0 = blockIdx.x * 512;
  const int tid = threadIdx.x;
  const int lane = tid & 63, l15 = lane & 15, quad = lane >> 4;
  const int wv = tid >> 6;
  const int nend = min(n0 + 512, N);

  f32x4 acc0 = (f32x4){0.f, 0.f, 0.f, 0.f};   // s rows 0..15
  f32x4 acc1 = (f32x4){0.f, 0.f, 0.f, 0.f};   // s rows 16..31

  for (int b = 0; b < NB; b++) {
    int lo = max(seg[b], n0), hi = min(seg[b + 1], nend);
    if (lo >= hi) continue;
    if (tid < 32) ln[tid] = 0.f;
    int c0lo = (lo - n0) & ~127;
    int c0hi = hi - n0;
    for (int c0 = c0lo; c0 < c0hi; c0 += 128) {
      __syncthreads();
      #pragma unroll
      for (int t = 0; t < 2; t++) {           // w: coalesced read, transposed+masked store
        int idx2 = tid + t * 256;             // 0..511
        int row = idx2 >> 2;                  // n-local 0..127
        int sc  = (idx2 & 3) * 8;
        int ng = n0 + c0 + row;
        short8 vh = (short8){0,0,0,0,0,0,0,0};
        short8 vl = (short8){0,0,0,0,0,0,0,0};
        if (ng >= lo && ng < hi) {
          size_t src = (size_t)ng * 256 + h * 32 + sc;
          vh = *(const short8*)&wh[src];
          vl = *(const short8*)&wl[src];
        }
        #pragma unroll
        for (int j = 0; j < 8; j++) {
          wth[sc + j][row] = vh[j];
          wtl[sc + j][row] = vl[j];
        }
      }
      #pragma unroll
      for (int t = 0; t < 4; t++) {           // fxT rows (64 d x 128 n)
        int idx2 = tid + t * 256;
        int row = idx2 >> 4, kc = (idx2 & 15) * 8;
        size_t src = (size_t)(h * 64 + row) * NP + n0 + c0 + kc;
        *(int4*)&fh[row][kc] = *(const int4*)&fxTh[src];
        *(int4*)&fl[row][kc] = *(const int4*)&fxTl[src];
      }
      __syncthreads();

      { // snorm from masked w tiles
        int s = tid >> 3, g = tid & 7;
        float sum = 0.f;
        #pragma unroll
        for (int i2 = 0; i2 < 16; i2++) {
          int nl = g * 16 + i2;
          sum += bf2f(wth[s][nl]) + bf2f(wtl[s][nl]);
        }
        atomicAdd(&ln[s], sum);
      }

      for (int k0 = 0; k0 < 128; k0 += 32) {
        int gbase = n0 + c0 + k0;
        if (gbase + 32 <= lo || gbase >= hi) continue;
        short8 a0h = *(const short8*)&wth[l15][k0 + quad * 8];
        short8 a0l = *(const short8*)&wtl[l15][k0 + quad * 8];
        short8 a1h = *(const short8*)&wth[16 + l15][k0 + quad * 8];
        short8 a1l = *(const short8*)&wtl[16 + l15][k0 + quad * 8];
        short8 bh = *(const short8*)&fh[wv * 16 + l15][k0 + quad * 8];
        short8 bl = *(const short8*)&fl[wv * 16 + l15][k0 + quad * 8];
        acc0 = __builtin_amdgcn_mfma_f32_16x16x32_bf16(a0h, bh, acc0, 0, 0, 0);
        acc0 = __builtin_amdgcn_mfma_f32_16x16x32_bf16(a0h, bl, acc0, 0, 0, 0);
        acc0 = __builtin_amdgcn_mfma_f32_16x16x32_bf16(a0l, bh, acc0, 0, 0, 0);
        acc1 = __builtin_amdgcn_mfma_f32_16x16x32_bf16(a1h, bh, acc1, 0, 0, 0);
        acc1 = __builtin_amdgcn_mfma_f32_16x16x32_bf16(a1h, bl, acc1, 0, 0, 0);
        acc1 = __builtin_amdgcn_mfma_f32_16x16x32_bf16(a1l, bh, acc1, 0, 0, 0);
      }
    }
    __syncthreads();
    size_t base = ((size_t)b * NH + h) * NS;
    #pragma unroll
    for (int r = 0; r < 4; r++) {
      atomicAdd(&stok[(base + quad * 4 + r) * ND + wv * 16 + l15], acc0[r]);
      atomicAdd(&stok[(base + 16 + quad * 4 + r) * ND + wv * 16 + l15], acc1[r]);
    }
    if (tid < 32) atomicAdd(&snorm[base + tid], ln[tid]);
    acc0 = (f32x4){0.f, 0.f, 0.f, 0.f};
    acc1 = (f32x4){0.f, 0.f, 0.f, 0.f};
    __syncthreads();
  }
}

// ---------------------------------------------------------------------------
// k_attn: per (b,h): normalize tokens, q/k/v, 32x32 attention, out_tok, then
// P[s][c] = sum_d out_tok[s][d]*Wout[h*64+d][c]; store P^T bf16 hi/lo.
// Latency-restructured: Wout h-panel async-DMA'd to LDS at entry; dd-outer
// q/k/v (W loads 8x fewer); wave-parallel softmax (8 lanes/row); P-phase
// reads Wout from LDS conflict-free (lane -> consecutive float4).
// ---------------------------------------------------------------------------
__global__ __launch_bounds__(256) void k_attn(
    const float* __restrict__ stok, const float* __restrict__ snorm,
    const float* __restrict__ Wq, const float* __restrict__ Wk,
    const float* __restrict__ Wv, const float* __restrict__ Wout,
    short* __restrict__ PTh, short* __restrict__ PTl)
{
  __shared__ __align__(16) float st[32][68];
  __shared__ __align__(16) float qs[32][68];
  __shared__ __align__(16) float ks[32][68];
  __shared__ __align__(16) float vs[32][68];
  __shared__ __align__(16) float at[32][36];
  __shared__ __align__(16) float ot[32][68];
  __shared__ __align__(16) float wo[64][256];   // Wout h-panel, 64 KB

  const int bh = blockIdx.x;
  const int b = bh >> 3, h = bh & 7;
  const int tid = threadIdx.x;
  const int lane = tid & 63;
  const int wv = tid >> 6;

  // async-stage Wout panel (h-slice, 64x256 f32 = 64 KB) into wo; latency
  // hides behind normalize + qkv (first consumer is the P phase; every
  // __syncthreads drains vmcnt).
  {
    const float* wsrc = Wout + (size_t)h * 16384;
    float* wdst = &wo[0][0];
    #pragma unroll
    for (int r = 0; r < 16; r++) {
      int off = r * 1024 + wv * 256;            // floats; wave-uniform
      gl_lds16(wsrc + off + lane * 4, wdst + off);
    }
  }

  // normalize tokens into st
  for (int i = tid; i < 2048; i += 256) {
    int ss = i >> 6, dd = i & 63;
    float nrm = snorm[(size_t)bh * NS + ss] + 1e-5f;
    st[ss][dd] = stok[(size_t)bh * 2048 + i] / nrm;
  }
  __syncthreads();

  // qkv: wave wv owns ss = wv*8..wv*8+7; lane = e.  dd-outer: one W load per
  // (matrix, dd) reused across 8 ss (was 8x redundant).
  {
    float aq[8], ak[8], av[8];
    #pragma unroll
    for (int i = 0; i < 8; i++) { aq[i] = 0.f; ak[i] = 0.f; av[i] = 0.f; }
    for (int ch = 0; ch < 16; ch++) {
      float4 sv[8];
      #pragma unroll
      for (int i = 0; i < 8; i++) sv[i] = *(const float4*)&st[wv * 8 + i][ch * 4];
      #pragma unroll
      for (int d = 0; d < 4; d++) {
        int dd = ch * 4 + d;
        float wq = Wq[dd * 64 + lane];
        float wk = Wk[dd * 64 + lane];
        float wvv = Wv[dd * 64 + lane];
        #pragma unroll
        for (int i = 0; i < 8; i++) {
          float sd = (d == 0) ? sv[i].x : (d == 1) ? sv[i].y : (d == 2) ? sv[i].z : sv[i].w;
          aq[i] = fmaf(sd, wq, aq[i]);
          ak[i] = fmaf(sd, wk, ak[i]);
          av[i] = fmaf(sd, wvv, av[i]);
        }
      }
    }
    #pragma unroll
    for (int i = 0; i < 8; i++) {
      qs[wv * 8 + i][lane] = aq[i];
      ks[wv * 8 + i][lane] = ak[i];
      vs[wv * 8 + i][lane] = av[i];
    }
  }
  __syncthreads();

  // scores: thread -> (si, tj0..tj0+3)
  {
    const int si = tid >> 3, tj0 = (tid & 7) * 4;
    float a0 = 0.f, a1 = 0.f, a2 = 0.f, a3 = 0.f;
    for (int ch = 0; ch < 16; ch++) {
      float4 q4 = *(const float4*)&qs[si][ch * 4];
      float4 k0 = *(const float4*)&ks[tj0 + 0][ch * 4];
      float4 k1 = *(const float4*)&ks[tj0 + 1][ch * 4];
      float4 k2 = *(const float4*)&ks[tj0 + 2][ch * 4];
      float4 k3 = *(const float4*)&ks[tj0 + 3][ch * 4];
      a0 += q4.x * k0.x + q4.y * k0.y + q4.z * k0.z + q4.w * k0.w;
      a1 += q4.x * k1.x + q4.y * k1.y + q4.z * k1.z + q4.w * k1.w;
      a2 += q4.x * k2.x + q4.y * k2.y + q4.z * k2.z + q4.w * k2.w;
      a3 += q4.x * k3.x + q4.y * k3.y + q4.z * k3.z + q4.w * k3.w;
    }
    const float scale = 0.125f;
    *(float4*)&at[si][tj0] = (float4){a0 * scale, a1 * scale, a2 * scale, a3 * scale};
  }
  __syncthreads();

  // softmax: 8 lanes per row, 4 cols each; shfl_xor width-8 reductions
  {
    const int row = tid >> 3, jb = (tid & 7) * 4;
    float4 v = *(const float4*)&at[row][jb];
    float m = fmaxf(fmaxf(v.x, v.y), fmaxf(v.z, v.w));
    #pragma unroll
    for (int off = 1; off < 8; off <<= 1) m = fmaxf(m, __shfl_xor(m, off, 8));
    float e0 = __expf(v.x - m), e1 = __expf(v.y - m);
    float e2 = __expf(v.z - m), e3 = __expf(v.w - m);
    float s = e0 + e1 + e2 + e3;
    #pragma unroll
    for (int off = 1; off < 8; off <<= 1) s += __shfl_xor(s, off, 8);
    float inv = 1.f / s;
    *(float4*)&at[row][jb] = (float4){e0 * inv, e1 * inv, e2 * inv, e3 * inv};
  }
  __syncthreads();

  // ot[ss][e] = sum_tj at[ss][tj] * vs[tj][e]; tj-outer chunks of 4
  {
    float acc[8];
    #pragma unroll
    for (int i = 0; i < 8; i++) acc[i] = 0.f;
    for (int ch = 0; ch < 8; ch++) {
      float v0 = vs[ch * 4 + 0][lane];
      float v1 = vs[ch * 4 + 1][lane];
      float v2 = vs[ch * 4 + 2][lane];
      float v3 = vs[ch * 4 + 3][lane];
      #pragma unroll
      for (int i = 0; i < 8; i++) {
        float4 a4 = *(const float4*)&at[wv * 8 + i][ch * 4];
        acc[i] += a4.x * v0 + a4.y * v1 + a4.z * v2 + a4.w * v3;
      }
    }
    #pragma unroll
    for (int i = 0; i < 8; i++) ot[wv * 8 + i][lane] = acc[i];
  }
  __syncthreads();

  // P phase: thread owns (8 s = wv*8.., 4 c = c0..c0+3); Wout from LDS.
  // c0 = 4*(lane&31) + 128*(lane>>5): lanes read consecutive float4s of the
  // wo row (2-way bank alias = free); ot reads are wave-broadcast.
  {
    const int c0 = 4 * (lane & 31) + 128 * (lane >> 5);
    float pacc[8][4];
    #pragma unroll
    for (int i = 0; i < 8; i++)
      #pragma unroll
      for (int c = 0; c < 4; c++) pacc[i][c] = 0.f;

    for (int ch = 0; ch < 16; ch++) {
      float4 w0 = *(const float4*)&wo[ch * 4 + 0][c0];
      float4 w1 = *(const float4*)&wo[ch * 4 + 1][c0];
      float4 w2 = *(const float4*)&wo[ch * 4 + 2][c0];
      float4 w3 = *(const float4*)&wo[ch * 4 + 3][c0];
      #pragma unroll
      for (int i = 0; i < 8; i++) {
        float4 o4 = *(const float4*)&ot[wv * 8 + i][ch * 4];
        pacc[i][0] = fmaf(o4.x, w0.x, pacc[i][0]);
        pacc[i][1] = fmaf(o4.x, w0.y, pacc[i][1]);
        pacc[i][2] = fmaf(o4.x, w0.z, pacc[i][2]);
        pacc[i][3] = fmaf(o4.x, w0.w, pacc[i][3]);
        pacc[i][0] = fmaf(o4.y, w1.x, pacc[i][0]);
        pacc[i][1] = fmaf(o4.y, w1.y, pacc[i][1]);
        pacc[i][2] = fmaf(o4.y, w1.z, pacc[i][2]);
        pacc[i][3] = fmaf(o4.y, w1.w, pacc[i][3]);
        pacc[i][0] = fmaf(o4.z, w2.x, pacc[i][0]);
        pacc[i][1] = fmaf(o4.z, w2.y, pacc[i][1]);
        pacc[i][2] = fmaf(o4.z, w2.z, pacc[i][2]);
        pacc[i][3] = fmaf(o4.z, w2.w, pacc[i][3]);
        pacc[i][0] = fmaf(o4.w, w3.x, pacc[i][0]);
        pacc[i][1] = fmaf(o4.w, w3.y, pacc[i][1]);
        pacc[i][2] = fmaf(o4.w, w3.z, pacc[i][2]);
        pacc[i][3] = fmaf(o4.w, w3.w, pacc[i][3]);
      }
    }

    // write PT^T: for each of the 4 c, the 8 s values are contiguous -> short8
    #pragma unroll
    for (int cc = 0; cc < 4; cc++) {
      short8 hv, lv;
      #pragma unroll
      for (int i = 0; i < 8; i++) {
        float val = pacc[i][cc];
        short hi = f2bf(val);
        hv[i] = hi;
        lv[i] = f2bf(val - bf2f(hi));
      }
      size_t dst = ((size_t)b * NDIM + (c0 + cc)) * 256 + h * 32 + wv * 8;
      *(short8*)&PTh[dst] = hv;
      *(short8*)&PTl[dst] = lv;
    }
  }
}

// ---------------------------------------------------------------------------
// k_outw: out[n,c] = sum_{hs} w[n,hs] * PT[batch[n]][c][hs] + bout[c].
// ---------------------------------------------------------------------------
__global__ __launch_bounds__(256) void k_outw(
    const short* __restrict__ wh, const short* __restrict__ wl,
    const short* __restrict__ PTh, const short* __restrict__ PTl,
    const int* __restrict__ batch, const float* __restrict__ bout,
    float* __restrict__ out, int N)
{
  __shared__ short Ah[128][40];
  __shared__ short Al[128][40];
  __shared__ short Bh[128][40];
  __shared__ short Bl[128][40];
  __shared__ int b_sh[128];

  const int ct = blockIdx.x;
  const int row0 = blockIdx.y * 128;
  const int tid = threadIdx.x;
  const int lane = tid & 63, l15 = lane & 15, quad = lane >> 4;
  const int wv = tid >> 6, wm = wv & 1, wn = wv >> 1;
  const int ctbase = ct * 128;
  const int cnt = min(128, N - row0);

  if (tid < 128) b_sh[tid] = (tid < cnt) ? batch[row0 + tid] : -1;
  __syncthreads();

  f32x4 acc[4][4];
  #pragma unroll
  for (int i = 0; i < 4; i++)
    #pragma unroll
    for (int j = 0; j < 4; j++) acc[i][j] = (f32x4){0.f, 0.f, 0.f, 0.f};

  int i0 = 0;
  while (i0 < cnt) {
    int b = b_sh[i0];
    int j = i0;
    while (j < cnt && b_sh[j] == b) j++;

    for (int kt = 0; kt < 8; kt++) {
      #pragma unroll
      for (int t = 0; t < 2; t++) {
        int i = tid + t * 256;
        int row = i >> 2, kc = (i & 3) * 8;
        int4 vh = make_int4(0, 0, 0, 0), vl = make_int4(0, 0, 0, 0);
        if (row >= i0 && row < j) {
          size_t src = (size_t)(row0 + row) * 256 + kt * 32 + kc;
          vh = *(const int4*)&wh[src];
          vl = *(const int4*)&wl[src];
        }
        *(int4*)&Ah[row][kc] = vh;
        *(int4*)&Al[row][kc] = vl;
      }
      #pragma unroll
      for (int t = 0; t < 2; t++) {
        int i = tid + t * 256;
        int row = i >> 2, kc = (i & 3) * 8;
        size_t src = ((size_t)b * NDIM + ctbase + row) * 256 + kt * 32 + kc;
        *(int4*)&Bh[row][kc] = *(const int4*)&PTh[src];
        *(int4*)&Bl[row][kc] = *(const int4*)&PTl[src];
      }
      __syncthreads();

      short8 ah[4], al[4];
      #pragma unroll
      for (int mt = 0; mt < 4; mt++) {
        int m = wm * 64 + mt * 16 + l15;
        ah[mt] = *(const short8*)&Ah[m][quad * 8];
        al[mt] = *(const short8*)&Al[m][quad * 8];
      }
      #pragma unroll
      for (int nt = 0; nt < 4; nt++) {
        int n = wn * 64 + nt * 16 + l15;
        short8 bh = *(const short8*)&Bh[n][quad * 8];
        short8 bl = *(const short8*)&Bl[n][quad * 8];
        #pragma unroll
        for (int mt = 0; mt < 4; mt++) {
          acc[mt][nt] = __builtin_amdgcn_mfma_f32_16x16x32_bf16(ah[mt], bh, acc[mt][nt], 0, 0, 0);
          acc[mt][nt] = __builtin_amdgcn_mfma_f32_16x16x32_bf16(ah[mt], bl, acc[mt][nt], 0, 0, 0);
          acc[mt][nt] = __builtin_amdgcn_mfma_f32_16x16x32_bf16(al[mt], bh, acc[mt][nt], 0, 0, 0);
        }
      }
      __syncthreads();
    }
    i0 = j;
  }

  #pragma unroll
  for (int nt = 0; nt < 4; nt++) {
    int c = ctbase + wn * 64 + nt * 16 + l15;
    float bias = bout[c];
    #pragma unroll
    for (int mt = 0; mt < 4; mt++)
      #pragma unroll
      for (int r = 0; r < 4; r++) {
        int row = row0 + wm * 64 + mt * 16 + quad * 4 + r;
        if (row < N) out[(size_t)row * NDIM + c] = acc[mt][nt][r] + bias;
      }
  }
}

// ---------------------------------------------------------------------------
extern "C" void kernel_launch(void* const* d_in, const int* in_sizes, int n_in,
                              void* d_out, int out_size, void* d_ws, size_t ws_size,
                              hipStream_t stream) {
  const float* x      = (const float*)d_in[0];
  const int*   batch  = (const int*)d_in[1];
  const float* Wfx    = (const float*)d_in[2];
  const float* bfx    = (const float*)d_in[3];
  const float* Wx     = (const float*)d_in[4];
  const float* bx     = (const float*)d_in[5];
  const float* Wsl    = (const float*)d_in[6];
  const float* bsl    = (const float*)d_in[7];
  const float* gtemp  = (const float*)d_in[8];
  const float* Wq     = (const float*)d_in[9];
  const float* Wk     = (const float*)d_in[10];
  const float* Wv     = (const float*)d_in[11];
  const float* Wout   = (const float*)d_in[12];
  const float* bout   = (const float*)d_in[13];
  float* out = (float*)d_out;

  const int N = in_sizes[0] / NDIM;   // 30000

  float* stok  = (float*)d_ws;                     // 131072
  float* snorm = stok + 131072;                    // 2048
  float* bcomb = snorm + 2048;                     // 256
  int*   seg   = (int*)(bcomb + 256);              // 16
  short* Bt1h  = (short*)(seg + 16);               // 196608
  short* Bt1l  = Bt1h + 196608;
  short* Xh    = Bt1l + 196608;                    // N*256
  short* Xl    = Xh + 7680000;
  short* whb   = Xl + 7680000;                     // NP*256
  short* wlb   = whb + (size_t)NP * 256;
  short* fxTh  = wlb + (size_t)NP * 256;           // 512*NP
  short* fxTl  = fxTh + (size_t)512 * NP;
  short* PTh   = fxTl + (size_t)512 * NP;          // 524288
  short* PTl   = PTh + 524288;

  hipMemsetAsync(stok, 0, (size_t)(131072 + 2048) * sizeof(float), stream);

  k_xsplit<<<(N * 64 + 255) / 256, 256, 0, stream>>>(x, Xh, Xl, N * 64);

  k_prep<<<770, 256, 0, stream>>>(Wfx, Wx, bx, Wsl, bsl, Bt1h, Bt1l, bcomb, seg);

  k_segs<<<(N + 255) / 256, 256, 0, stream>>>(batch, seg, N);

  const int ntiles = (N + 127) / 128;               // 235
  const int qmax = (ntiles + 7) / 8;                // 30
  k_fxw<<<8 * qmax * 6, 512, 0, stream>>>(Xh, Xl, Bt1h, Bt1l, bfx, bcomb, gtemp,
                                          fxTh, fxTl, whb, wlb, N, ntiles);

  dim3 g2((N + 511) / 512, NH);
  k_scat<<<g2, 256, 0, stream>>>(whb, wlb, fxTh, fxTl, seg, stok, snorm, N);

  k_attn<<<NB * NH, 256, 0, stream>>>(stok, snorm, Wq, Wk, Wv, Wout, PTh, PTl);

  dim3 g5(2, (N + 127) / 128);
  k_outw<<<g5, 256, 0, stream>>>(whb, wlb, PTh, PTl, batch, bout, out, N);
}